// Round 2
// 96.304 us; speedup vs baseline: 1.0386x; 1.0386x over previous
//
#include <hip/hip_runtime.h>
#include <math.h>

#define NQ 10
#define NL 3
#define PI_F 3.14159265358979f
#define TPB 256   // 4 waves/block; ONE batch element per wave

typedef _Float16 f16x8 __attribute__((ext_vector_type(8)));
typedef _Float16 h2t  __attribute__((ext_vector_type(2)));
typedef float    f32x4 __attribute__((ext_vector_type(4)));

// Compiler memory barrier + LDS drain: optimizer cannot move LDS ops across,
// hardware guarantees all prior DS ops complete. (wave_barrier is NOT a memory
// fence — R11/R12 failed because typed loads were hoisted across stores.)
#define LDSFENCE asm volatile("s_waitcnt lgkmcnt(0)" ::: "memory")

// Composed CNOT-ring permutation (GF(2)-linear), compile-time only.
__host__ __device__ constexpr int cnot_chain_ce(int j) {
    for (int i = NQ - 1; i >= 0; --i) {
        int tq = (i + 1) % NQ;
        j ^= ((j >> (NQ - 1 - i)) & 1) << (NQ - 1 - tq);
    }
    return j;
}

// ---- S-layout bank swizzle (R13, kept in R14) ----------------------------
// slot(k) = φ(k) = k ^ g5(k>>5), GF(2)-linear, bijective on [0,1024).
// R14 note: R13's correctness failure was isolated to amdgpu_waves_per_eu(8,8)
// (forced 64-VGPR budget -> spills/AGPR copies around MFMA + asm fences, a
// miscompile trigger). The swizzle itself is a provably-equivalent bijective
// relabel of the wave-private S plane: IST stores φ(16*lane+J), GATH reads
// φ(P(k)) (by GF(2)-linearity of φ∘P), STL stores φ(k_out). Attribute reverted
// to (4,4); swizzle is the single variable vs the 100 µs baseline.
// g5 constants solved for three simultaneous conditions (enumeration-verified):
//  * GATH: φ-images of CNOT generators {P8,P16,P32,P64,P128}={12,24,48,96,192}
//    -> bank generators {12,24,17,18,11}: rank 5 => 32 distinct banks,
//    conflict-FREE for every gather instruction (quad 0/2 and 1/3 broadcast).
//  * IST:  φ bijective => exact 2-way (free per m136).
//  * STL:  quad bank offsets g5(2q) = {0,19,24,11}: two in [0,16), two in
//    [16,32) => exact 2-way (was 4-way under k+(k>>4)).
__host__ __device__ constexpr int g5f_ce(int h) {
    return ((h & 1) ? 1 : 0) ^ ((h & 2) ? 19 : 0) ^ ((h & 4) ? 24 : 0)
         ^ ((h & 8) ? 4 : 0) ^ ((h & 16) ? 2 : 0);
}
__host__ __device__ constexpr int phi_ce(int k) { return k ^ g5f_ce(k >> 5); }
// STL store offset: φ(256b) ^ φ(16r) (disjoint bit-fields => XOR-separable)
__host__ __device__ constexpr int stc_ce(int b, int r) {
    return phi_ce(256 * (b)) ^ phi_ce(16 * (r));
}

__device__ __forceinline__ unsigned pkh(float r, float i) {
    return __builtin_bit_cast(unsigned, __builtin_amdgcn_cvt_pkrtz(r, i));
}

// Build a B-fragment (f16x8): element e = selected f16 half of dw[e].
// psel picks lo halves (re-plane lanes) or hi halves (im-plane lanes).
__device__ __forceinline__ f16x8 mkfrag(unsigned d0, unsigned d1, unsigned d2,
                                        unsigned d3, unsigned d4, unsigned d5,
                                        unsigned d6, unsigned d7, unsigned sel) {
    uint4 u;
    u.x = __builtin_amdgcn_perm(d1, d0, sel);
    u.y = __builtin_amdgcn_perm(d3, d2, sel);
    u.z = __builtin_amdgcn_perm(d5, d4, sel);
    u.w = __builtin_amdgcn_perm(d7, d6, sel);
    return __builtin_bit_cast(f16x8, u);
}

// lane-xor exchange for the final reduction: 1,2,4,8 DPP; 16 swizzle; 32 shfl
template<int MASK>
__device__ __forceinline__ unsigned lxu(unsigned v) {
    if constexpr (MASK == 1)
        return (unsigned)__builtin_amdgcn_update_dpp(0, (int)v, 0xB1, 0xF, 0xF, true);
    else if constexpr (MASK == 2)
        return (unsigned)__builtin_amdgcn_update_dpp(0, (int)v, 0x4E, 0xF, 0xF, true);
    else if constexpr (MASK == 4) {
        int a = __builtin_amdgcn_update_dpp(0, (int)v, 0x1B, 0xF, 0xF, true);
        return (unsigned)__builtin_amdgcn_update_dpp(0, a, 0x141, 0xF, 0xF, true);
    } else if constexpr (MASK == 8) {
        int a = __builtin_amdgcn_update_dpp(0, (int)v, 0x141, 0xF, 0xF, true);
        return (unsigned)__builtin_amdgcn_update_dpp(0, a, 0x140, 0xF, 0xF, true);
    } else if constexpr (MASK == 16)
        return (unsigned)__builtin_amdgcn_ds_swizzle((int)v, 0x401F);
    else
        return (unsigned)__shfl_xor((int)v, 32, 64);
}
#define WR1(v, M) v += __builtin_bit_cast(float, lxu<M>(__builtin_bit_cast(unsigned, v)));
#define WRED(v) { WR1(v,1) WR1(v,2) WR1(v,4) WR1(v,8) WR1(v,16) WR1(v,32) }

#define FORALL16(F) F(0) F(1) F(2) F(3) F(4) F(5) F(6) F(7) \
                    F(8) F(9) F(10) F(11) F(12) F(13) F(14) F(15)
#define FORALLQ(F) F(0) F(1) F(2) F(3) F(4) F(5) F(6) F(7) F(8) F(9)

// ============ prep: fused gate matrices -> MFMA A-fragments (R10-verified) ============
__global__ void vq_prep(const float* __restrict__ w, uint4* __restrict__ frag,
                        float* __restrict__ qcoef) {
    __shared__ float msh[NL * NQ][8];
    const int tid = threadIdx.x;
    if (tid < NL * NQ) {
        const float* wp = w + tid * 3;
        float sa = __sinf(wp[0]*0.5f), ca = __cosf(wp[0]*0.5f);
        float sb = __sinf(wp[1]*0.5f), cb = __cosf(wp[1]*0.5f);
        float sc = __sinf(wp[2]*0.5f), cc = __cosf(wp[2]*0.5f);
        float c00r = cb*ca,  c00i =  sa*sb;
        float c01r = -sb*ca, c01i = -cb*sa;
        float c10r =  sb*ca, c10i = -cb*sa;
        float c11r =  cb*ca, c11i = -sb*sa;
        float m[8];
        m[0] = cc*c00r + sc*c00i;  m[1] = cc*c00i - sc*c00r;
        m[2] = cc*c01r + sc*c01i;  m[3] = cc*c01i - sc*c01r;
        m[4] = cc*c10r - sc*c10i;  m[5] = cc*c10i + sc*c10r;
        m[6] = cc*c11r - sc*c11i;  m[7] = cc*c11i + sc*c11r;
#pragma unroll
        for (int j = 0; j < 8; ++j) msh[tid][j] = m[j];
        const int l = tid / NQ, q = tid % NQ;
        if (q < 2)
#pragma unroll
            for (int j = 0; j < 8; ++j) qcoef[(l*2 + q)*8 + j] = m[j];
    }
    __syncthreads();
    const int lane = tid & 63, wg = tid >> 6;
    const int mrow = lane & 15, quad = lane >> 4;
#pragma unroll 1
    for (int c = 0; c < 3; ++c) {
        const int id = c*4 + wg;            // id = l*4 + s*2 + v
        const int l = id >> 2, s = (id >> 1) & 1, v = id & 1;
        const int qb = s ? 2 : 6;
        unsigned pd[4];
#pragma unroll
        for (int d = 0; d < 4; ++d) {
            float hv[2];
#pragma unroll
            for (int h = 0; h < 2; ++h) {
                const int k = quad*8 + 2*d + h;
                const int col = k & 15;
                float er = 1.f, ei = 0.f;
#pragma unroll
                for (int p = 0; p < 4; ++p) {
                    const float* mm = msh[l*NQ + qb + p];
                    const int rb = (mrow >> (3-p)) & 1, cb2 = (col >> (3-p)) & 1;
                    const float gr = mm[(rb*2 + cb2)*2], gi = mm[(rb*2 + cb2)*2 + 1];
                    const float nr = er*gr - ei*gi, ni = er*gi + ei*gr;
                    er = nr; ei = ni;
                }
                hv[h] = (k < 16) ? (v ? ei : er) : (v ? er : -ei);
            }
            h2t hh; hh.x = (_Float16)hv[0]; hh.y = (_Float16)hv[1];
            pd[d] = __builtin_bit_cast(unsigned, hh);
        }
        frag[id*64 + lane] = make_uint4(pd[0], pd[1], pd[2], pd[3]);
    }
}

// ============ main kernel ============
// S  (inter-layer): slot(k) = φ(k) = k ^ g5(k>>5); perm applied at GATH read.
//    φ is GF(2)-linear so GATH addr = φ(PBv) ^ constexpr — 1 XOR/load.
// S' (intra-layer): j'-major slot = 68*j' + t (unchanged). ALL LDS accesses
//    are `unsigned` (single TBAA type) + LDSFENCE at every store->load boundary.

#define DECLF(q) float f0_##q, f1_##q;
#define MKF(q) { float e_ = __expf(2.0f * xr[q]); \
    float h_ = (1.0f - 2.0f / (e_ + 1.0f)) * (PI_F * 0.5f); \
    f1_##q = __sinf(h_); f0_##q = __cosf(h_); }

#define IST(J) { float a_ = pr \
    * ((((J) >> 3) & 1) ? f1_6 : f0_6) * ((((J) >> 2) & 1) ? f1_7 : f0_7) \
    * ((((J) >> 1) & 1) ? f1_8 : f0_8) * (((J) & 1) ? f1_9 : f0_9); \
    P[ibase ^ (J)] = pkh(a_, 0.0f); }

// stage-A gather with perm + φ fused: slot = φ(PBv) ^ φ(P(256b) ^ P(i))
// bank generators {24,17,18,11,12} rank-5 => conflict-free (enumeration)
#define LDA1(b,i) { constexpr int sc_ = phi_ce(cnot_chain_ce((b)*256) ^ cnot_chain_ce(i)); \
    dw##i = P[PBvPhi ^ sc_]; }
#define GATH(b) LDA1(b,0) LDA1(b,1) LDA1(b,2) LDA1(b,3) LDA1(b,4) LDA1(b,5) LDA1(b,6) LDA1(b,7) \
    fr##b = mkfrag(dw0,dw1,dw2,dw3,dw4,dw5,dw6,dw7,psel);

// stage-A MFMA + store to S' (j'-major): slot = 68*(4quad+r) + 16b + n
// per-instruction bank = (16*quad + n) mod 32 -> exact 2-way, free
#define MMA_A(b) { \
    f32x4 cr_ = __builtin_amdgcn_mfma_f32_16x16x32_f16(aAr, fr##b, z4, 0, 0, 0); \
    f32x4 ci_ = __builtin_amdgcn_mfma_f32_16x16x32_f16(aAi, fr##b, z4, 0, 0, 0); \
    P[sA + 16*(b)      ] = pkh(cr_.x, ci_.x); \
    P[sA + 16*(b) +  68] = pkh(cr_.y, ci_.y); \
    P[sA + 16*(b) + 136] = pkh(cr_.z, ci_.z); \
    P[sA + 16*(b) + 204] = pkh(cr_.w, ci_.w); }

// stage-B gather: 8 ADJACENT unsigned loads (slot = 68n + 8q1 + 16b + i) --
// same TBAA type as all stores; backend may fuse into ds_read_b128.
#define GATB(b) { const int gb_ = 68*n + 8*q1 + 16*(b); \
    dw0 = P[gb_    ]; dw1 = P[gb_ + 1]; dw2 = P[gb_ + 2]; dw3 = P[gb_ + 3]; \
    dw4 = P[gb_ + 4]; dw5 = P[gb_ + 5]; dw6 = P[gb_ + 6]; dw7 = P[gb_ + 7]; \
    fr##b = mkfrag(dw0,dw1,dw2,dw3,dw4,dw5,dw6,dw7,psel); }

#define MMA_B(b) \
    car##b = __builtin_amdgcn_mfma_f32_16x16x32_f16(aBr, fr##b, z4, 0, 0, 0); \
    cai##b = __builtin_amdgcn_mfma_f32_16x16x32_f16(aBi, fr##b, z4, 0, 0, 0);

// complex 2x2 gate on C-accumulator block pair (f32)
#define CGATE(pa, pb, qp) { \
    const float g0_=(qp)[0], g1_=(qp)[1], g2_=(qp)[2], g3_=(qp)[3]; \
    const float g4_=(qp)[4], g5_=(qp)[5], g6_=(qp)[6], g7_=(qp)[7]; \
    f32x4 ar_ = car##pa, ai_ = cai##pa, br_ = car##pb, bi_ = cai##pb; \
    car##pa = g0_*ar_ - g1_*ai_ + g2_*br_ - g3_*bi_; \
    cai##pa = g0_*ai_ + g1_*ar_ + g2_*bi_ + g3_*br_; \
    car##pb = g4_*ar_ - g5_*ai_ + g6_*br_ - g7_*bi_; \
    cai##pb = g4_*ai_ + g5_*ar_ + g6_*bi_ + g7_*br_; }

// layer store to S under φ: k_out = 256b + 64quad + 16r + n
// slot = stb ^ stc_ce(b,r); quad offsets {0,19,24,11} => exact 2-way, free
#define STL(b) { P[stb ^ stc_ce(b,0)] = pkh(car##b.x, cai##b.x); \
                 P[stb ^ stc_ce(b,1)] = pkh(car##b.y, cai##b.y); \
                 P[stb ^ stc_ce(b,2)] = pkh(car##b.z, cai##b.z); \
                 P[stb ^ stc_ce(b,3)] = pkh(car##b.w, cai##b.w); }

#define ROD(b, r, comp) { const float p_ = car##b.comp*car##b.comp + cai##b.comp*cai##b.comp; \
    Sx += p_; \
    aq0 += ((b)&2) ? -p_ : p_;  aq1 += ((b)&1) ? -p_ : p_; \
    aq4 += ((r)&2) ? -p_ : p_;  aq5 += ((r)&1) ? -p_ : p_; }
#define ROB(b) ROD(b,0,x) ROD(b,1,y) ROD(b,2,z) ROD(b,3,w)

__global__ __launch_bounds__(TPB)
__attribute__((amdgpu_waves_per_eu(4, 4)))   // R14: (8,8) reverted — forcing a
// 64-VGPR budget (live state ~70-80 regs at MMA_B) caused spills/AGPR copies
// around MFMA + asm fences and a correctness failure (absmax 0.13). VGPR=52
// already permits 8 waves/EU resource-wise; (4,4) never HW-capped occupancy.
void vq_main(const float* __restrict__ x, const uint4* __restrict__ frag,
             const float* __restrict__ qcoef, float* __restrict__ out) {
    __shared__ __align__(16) unsigned pl[4][1088];   // wave-private planes
    const int tid = threadIdx.x, wv = tid >> 6, lane = tid & 63;
    unsigned* P = pl[wv];
    const int elem = __builtin_amdgcn_readfirstlane(blockIdx.x * 4 + wv);
    const int n = lane & 15, quad = lane >> 4, q1 = quad & 1;
    const unsigned psel = (lane & 32) ? 0x07060302u : 0x05040100u;

    // perm+swizzle addressing: φ(P(k)) is GF(2)-linear => build φ(PBv) directly
    int PnPhi = 0;
#pragma unroll
    for (int mm = 0; mm < 4; ++mm)
        PnPhi ^= ((n >> mm) & 1) ? phi_ce(cnot_chain_ce(16 << mm)) : 0;
    const int PBvPhi = PnPhi ^ (q1 ? phi_ce(cnot_chain_ce(8)) : 0);
    const int sA  = 272*quad + n;                      // stage-A store base (S')
    const int stb = (quad << 6) ^ g5f_ce(2*quad) ^ n;  // layer store base (S, φ)
    const int ibase = (lane << 4) ^ g5f_ce(lane >> 1); // init store base (S, φ)

    // ---- init: plain product state at slot = φ(k) (perm applied at GATH)
    const float* xr = x + elem * NQ;
    FORALLQ(DECLF)
    FORALLQ(MKF)
    {
        const float pr = (((lane>>5)&1) ? f1_0 : f0_0) * (((lane>>4)&1) ? f1_1 : f0_1)
                       * (((lane>>3)&1) ? f1_2 : f0_2) * (((lane>>2)&1) ? f1_3 : f0_3)
                       * (((lane>>1)&1) ? f1_4 : f0_4) * ((lane&1) ? f1_5 : f0_5);
        FORALL16(IST)
    }
    LDSFENCE;

    f32x4 car0, car1, car2, car3, cai0, cai1, cai2, cai3;
    const f32x4 z4 = {0.f, 0.f, 0.f, 0.f};

#pragma unroll 1
    for (int l = 0; l < NL; ++l) {
        const uint4* fp = frag + l*4*64;
        const f16x8 aAr = __builtin_bit_cast(f16x8, fp[lane]);
        const f16x8 aAi = __builtin_bit_cast(f16x8, fp[64 + lane]);
        const f16x8 aBr = __builtin_bit_cast(f16x8, fp[128 + lane]);
        const f16x8 aBi = __builtin_bit_cast(f16x8, fp[192 + lane]);
        const float* qc = qcoef + l*16;
        unsigned dw0, dw1, dw2, dw3, dw4, dw5, dw6, dw7;
        f16x8 fr0, fr1, fr2, fr3;

        // stage A: gather (perm+φ fused) ALL blocks, then MFMA+store into S'
        GATH(0) GATH(1) GATH(2) GATH(3)
        LDSFENCE;                          // all S reads done before S' overwrites
        MMA_A(0) MMA_A(1) MMA_A(2) MMA_A(3)
        LDSFENCE;                          // S' stores done before S' reads

        // stage B: adjacent loads from S', MFMA, qubit-0/1 register gates
        GATB(0) GATB(1) GATB(2) GATB(3)
        LDSFENCE;                          // S' reads done before STL overwrites
        MMA_B(0) MMA_B(1) MMA_B(2) MMA_B(3)
        CGATE(0, 1, qc + 8)  CGATE(2, 3, qc + 8)   // qubit 1 (t_hi bit0)
        CGATE(0, 2, qc)      CGATE(1, 3, qc)       // qubit 0 (t_hi bit1)
        if (l < NL - 1) {
            STL(0) STL(1) STL(2) STL(3)            // φ-layout store into S
            LDSFENCE;                      // S stores done before next GATH
        }
    }

    // ---- readout from C regs: k = (16b + 4quad + r)*16 + n
    float Sx = 0.f, aq0 = 0.f, aq1 = 0.f, aq4 = 0.f, aq5 = 0.f;
    ROB(0) ROB(1) ROB(2) ROB(3)
    float w2 = ((lane>>5)&1) ? -Sx : Sx;
    float w3 = ((lane>>4)&1) ? -Sx : Sx;
    float w6 = ((lane>>3)&1) ? -Sx : Sx;
    float w7 = ((lane>>2)&1) ? -Sx : Sx;
    float w8 = ((lane>>1)&1) ? -Sx : Sx;
    float w9 = (lane&1) ? -Sx : Sx;
    WRED(aq0) WRED(aq1) WRED(w2) WRED(w3) WRED(aq4)
    WRED(aq5) WRED(w6) WRED(w7) WRED(w8) WRED(w9)
    if (lane == 0) {
        float* op = out + elem * NQ;
        op[0] = aq0; op[1] = aq1; op[2] = w2; op[3] = w3; op[4] = aq4;
        op[5] = aq5; op[6] = w6; op[7] = w7; op[8] = w8; op[9] = w9;
    }
}

extern "C" void kernel_launch(void* const* d_in, const int* in_sizes, int n_in,
                              void* d_out, int out_size, void* d_ws, size_t ws_size,
                              hipStream_t stream) {
    const float* x = (const float*)d_in[0];   // (16384, 10) fp32
    const float* w = (const float*)d_in[1];   // (3, 10, 3) fp32
    float* out = (float*)d_out;               // (16384, 10) fp32
    uint4* frag = (uint4*)d_ws;               // 768 uint4 = 12 KB A-fragments
    float* qcoef = (float*)((char*)d_ws + 768 * sizeof(uint4));   // 48 floats
    const int B = in_sizes[0] / NQ;           // 16384
    vq_prep<<<dim3(1), dim3(TPB), 0, stream>>>(w, frag, qcoef);
    vq_main<<<dim3(B / 4), dim3(TPB), 0, stream>>>(x, frag, qcoef, out);
}

// Round 3
// 95.919 us; speedup vs baseline: 1.0427x; 1.0040x over previous
//
#include <hip/hip_runtime.h>
#include <math.h>

#define NQ 10
#define NL 3
#define PI_F 3.14159265358979f
#define TPB 256   // 4 waves/block; ONE batch element per wave

typedef _Float16 f16x8 __attribute__((ext_vector_type(8)));
typedef _Float16 h2t  __attribute__((ext_vector_type(2)));
typedef float    f32x4 __attribute__((ext_vector_type(4)));
typedef float    f32x2 __attribute__((ext_vector_type(2)));

// Compiler memory barrier + LDS drain: optimizer cannot move LDS ops across,
// hardware guarantees all prior DS ops complete. (wave_barrier is NOT a memory
// fence — R11/R12 failed because typed loads were hoisted across stores.)
#define LDSFENCE asm volatile("s_waitcnt lgkmcnt(0)" ::: "memory")

// Composed CNOT-ring permutation (GF(2)-linear), compile-time only.
__host__ __device__ constexpr int cnot_chain_ce(int j) {
    for (int i = NQ - 1; i >= 0; --i) {
        int tq = (i + 1) % NQ;
        j ^= ((j >> (NQ - 1 - i)) & 1) << (NQ - 1 - tq);
    }
    return j;
}

// ---- S-layout bank swizzle (R13/R14-verified) ----------------------------
// slot(k) = φ(k) = k ^ g5(k>>5), GF(2)-linear, bijective on [0,1024).
// GATH bank generators {12,24,17,18,11}: rank 5 => conflict-free gathers.
// IST exact 2-way (free); STL exact 2-way. Measured: conflicts 1.21e7->1.57e6.
__host__ __device__ constexpr int g5f_ce(int h) {
    return ((h & 1) ? 1 : 0) ^ ((h & 2) ? 19 : 0) ^ ((h & 4) ? 24 : 0)
         ^ ((h & 8) ? 4 : 0) ^ ((h & 16) ? 2 : 0);
}
__host__ __device__ constexpr int phi_ce(int k) { return k ^ g5f_ce(k >> 5); }
// STL store offset: φ(256b) ^ φ(16r) (disjoint bit-fields => XOR-separable)
__host__ __device__ constexpr int stc_ce(int b, int r) {
    return phi_ce(256 * (b)) ^ phi_ce(16 * (r));
}

__device__ __forceinline__ unsigned pkh(float r, float i) {
    return __builtin_bit_cast(unsigned, __builtin_amdgcn_cvt_pkrtz(r, i));
}

// f32x4 <-> f32x2 half helpers (register-aliasing; no data movement expected)
__device__ __forceinline__ f32x2 lo2(f32x4 v) { f32x2 r; r.x = v.x; r.y = v.y; return r; }
__device__ __forceinline__ f32x2 hi2(f32x4 v) { f32x2 r; r.x = v.z; r.y = v.w; return r; }
__device__ __forceinline__ f32x4 cat4(f32x2 a, f32x2 b) {
    f32x4 r; r.x = a.x; r.y = a.y; r.z = b.x; r.w = b.y; return r;
}

// Build a B-fragment (f16x8): element e = selected f16 half of dw[e].
// psel picks lo halves (re-plane lanes) or hi halves (im-plane lanes).
__device__ __forceinline__ f16x8 mkfrag(unsigned d0, unsigned d1, unsigned d2,
                                        unsigned d3, unsigned d4, unsigned d5,
                                        unsigned d6, unsigned d7, unsigned sel) {
    uint4 u;
    u.x = __builtin_amdgcn_perm(d1, d0, sel);
    u.y = __builtin_amdgcn_perm(d3, d2, sel);
    u.z = __builtin_amdgcn_perm(d5, d4, sel);
    u.w = __builtin_amdgcn_perm(d7, d6, sel);
    return __builtin_bit_cast(f16x8, u);
}

// lane-xor exchange for the final reduction: 1,2,4,8 DPP; 16 swizzle; 32 shfl
template<int MASK>
__device__ __forceinline__ unsigned lxu(unsigned v) {
    if constexpr (MASK == 1)
        return (unsigned)__builtin_amdgcn_update_dpp(0, (int)v, 0xB1, 0xF, 0xF, true);
    else if constexpr (MASK == 2)
        return (unsigned)__builtin_amdgcn_update_dpp(0, (int)v, 0x4E, 0xF, 0xF, true);
    else if constexpr (MASK == 4) {
        int a = __builtin_amdgcn_update_dpp(0, (int)v, 0x1B, 0xF, 0xF, true);
        return (unsigned)__builtin_amdgcn_update_dpp(0, a, 0x141, 0xF, 0xF, true);
    } else if constexpr (MASK == 8) {
        int a = __builtin_amdgcn_update_dpp(0, (int)v, 0x141, 0xF, 0xF, true);
        return (unsigned)__builtin_amdgcn_update_dpp(0, a, 0x140, 0xF, 0xF, true);
    } else if constexpr (MASK == 16)
        return (unsigned)__builtin_amdgcn_ds_swizzle((int)v, 0x401F);
    else
        return (unsigned)__shfl_xor((int)v, 32, 64);
}
#define WR1(v, M) v += __builtin_bit_cast(float, lxu<M>(__builtin_bit_cast(unsigned, v)));
#define WRED(v) { WR1(v,1) WR1(v,2) WR1(v,4) WR1(v,8) WR1(v,16) WR1(v,32) }
// R15: shared butterfly with difference-spawn. At each level, the sum-channel
// and the signed output share the same shuffle; lane 0 (all bits 0) always
// carries the + convention, so per-lane sign skew in D cancels at readout.
#define SPAWN(M, D) { float t_ = __builtin_bit_cast(float, lxu<M>(__builtin_bit_cast(unsigned, cur))); \
    D = cur - t_; cur += t_; }

#define FORALL16(F) F(0) F(1) F(2) F(3) F(4) F(5) F(6) F(7) \
                    F(8) F(9) F(10) F(11) F(12) F(13) F(14) F(15)
#define FORALLQ(F) F(0) F(1) F(2) F(3) F(4) F(5) F(6) F(7) F(8) F(9)

// ============ prep: fused gate matrices -> MFMA A-fragments (R10-verified) ============
__global__ void vq_prep(const float* __restrict__ w, uint4* __restrict__ frag,
                        float* __restrict__ qcoef) {
    __shared__ float msh[NL * NQ][8];
    const int tid = threadIdx.x;
    if (tid < NL * NQ) {
        const float* wp = w + tid * 3;
        float sa = __sinf(wp[0]*0.5f), ca = __cosf(wp[0]*0.5f);
        float sb = __sinf(wp[1]*0.5f), cb = __cosf(wp[1]*0.5f);
        float sc = __sinf(wp[2]*0.5f), cc = __cosf(wp[2]*0.5f);
        float c00r = cb*ca,  c00i =  sa*sb;
        float c01r = -sb*ca, c01i = -cb*sa;
        float c10r =  sb*ca, c10i = -cb*sa;
        float c11r =  cb*ca, c11i = -sb*sa;
        float m[8];
        m[0] = cc*c00r + sc*c00i;  m[1] = cc*c00i - sc*c00r;
        m[2] = cc*c01r + sc*c01i;  m[3] = cc*c01i - sc*c01r;
        m[4] = cc*c10r - sc*c10i;  m[5] = cc*c10i + sc*c10r;
        m[6] = cc*c11r - sc*c11i;  m[7] = cc*c11i + sc*c11r;
#pragma unroll
        for (int j = 0; j < 8; ++j) msh[tid][j] = m[j];
        const int l = tid / NQ, q = tid % NQ;
        if (q < 2)
#pragma unroll
            for (int j = 0; j < 8; ++j) qcoef[(l*2 + q)*8 + j] = m[j];
    }
    __syncthreads();
    const int lane = tid & 63, wg = tid >> 6;
    const int mrow = lane & 15, quad = lane >> 4;
#pragma unroll 1
    for (int c = 0; c < 3; ++c) {
        const int id = c*4 + wg;            // id = l*4 + s*2 + v
        const int l = id >> 2, s = (id >> 1) & 1, v = id & 1;
        const int qb = s ? 2 : 6;
        unsigned pd[4];
#pragma unroll
        for (int d = 0; d < 4; ++d) {
            float hv[2];
#pragma unroll
            for (int h = 0; h < 2; ++h) {
                const int k = quad*8 + 2*d + h;
                const int col = k & 15;
                float er = 1.f, ei = 0.f;
#pragma unroll
                for (int p = 0; p < 4; ++p) {
                    const float* mm = msh[l*NQ + qb + p];
                    const int rb = (mrow >> (3-p)) & 1, cb2 = (col >> (3-p)) & 1;
                    const float gr = mm[(rb*2 + cb2)*2], gi = mm[(rb*2 + cb2)*2 + 1];
                    const float nr = er*gr - ei*gi, ni = er*gi + ei*gr;
                    er = nr; ei = ni;
                }
                hv[h] = (k < 16) ? (v ? ei : er) : (v ? er : -ei);
            }
            h2t hh; hh.x = (_Float16)hv[0]; hh.y = (_Float16)hv[1];
            pd[d] = __builtin_bit_cast(unsigned, hh);
        }
        frag[id*64 + lane] = make_uint4(pd[0], pd[1], pd[2], pd[3]);
    }
}

// ============ main kernel ============
// S  (inter-layer): slot(k) = φ(k) = k ^ g5(k>>5); perm applied at GATH read.
// S' (intra-layer): j'-major slot = 68*j' + t (unchanged). ALL LDS accesses
//    are `unsigned` (single TBAA type) + LDSFENCE at every store->load boundary.
// R15: VALU-count reduction round (kernel is issue-bound: VALUBusy 75%,
// MfmaUtil 11%, HBM 0.4%, conflicts at noise). No layout/sync changes.

#define DECLF(q) float f0_##q, f1_##q;
#define MKF(q) { float e_ = __expf(2.0f * xr[q]); \
    float h_ = (1.0f - 2.0f / (e_ + 1.0f)) * (PI_F * 0.5f); \
    f1_##q = __sinf(h_); f0_##q = __cosf(h_); }

// R15: factored init products — cc[J>>2] * bb[J&3] (literal J => static index)
#define IST(J) { float a_ = cc[(J) >> 2] * bb[(J) & 3]; \
    P[ibase ^ (J)] = pkh(a_, 0.0f); }

// stage-A gather with perm + φ fused: slot = φ(PBv) ^ φ(P(256b) ^ P(i))
// bank generators {24,17,18,11,12} rank-5 => conflict-free (enumeration)
#define LDA1(b,i) { constexpr int sc_ = phi_ce(cnot_chain_ce((b)*256) ^ cnot_chain_ce(i)); \
    dw##i = P[PBvPhi ^ sc_]; }
#define GATH(b) LDA1(b,0) LDA1(b,1) LDA1(b,2) LDA1(b,3) LDA1(b,4) LDA1(b,5) LDA1(b,6) LDA1(b,7) \
    fr##b = mkfrag(dw0,dw1,dw2,dw3,dw4,dw5,dw6,dw7,psel);

// stage-A MFMA + store to S' (j'-major): slot = 68*(4quad+r) + 16b + n
// per-instruction bank = (16*quad + n) mod 32 -> exact 2-way, free
#define MMA_A(b) { \
    f32x4 cr_ = __builtin_amdgcn_mfma_f32_16x16x32_f16(aAr, fr##b, z4, 0, 0, 0); \
    f32x4 ci_ = __builtin_amdgcn_mfma_f32_16x16x32_f16(aAi, fr##b, z4, 0, 0, 0); \
    P[sA + 16*(b)      ] = pkh(cr_.x, ci_.x); \
    P[sA + 16*(b) +  68] = pkh(cr_.y, ci_.y); \
    P[sA + 16*(b) + 136] = pkh(cr_.z, ci_.z); \
    P[sA + 16*(b) + 204] = pkh(cr_.w, ci_.w); }

// stage-B gather: 8 ADJACENT unsigned loads (slot = 68n + 8q1 + 16b + i) --
// same TBAA type as all stores; backend may fuse into ds_read_b128.
#define GATB(b) { const int gb_ = 68*n + 8*q1 + 16*(b); \
    dw0 = P[gb_    ]; dw1 = P[gb_ + 1]; dw2 = P[gb_ + 2]; dw3 = P[gb_ + 3]; \
    dw4 = P[gb_ + 4]; dw5 = P[gb_ + 5]; dw6 = P[gb_ + 6]; dw7 = P[gb_ + 7]; \
    fr##b = mkfrag(dw0,dw1,dw2,dw3,dw4,dw5,dw6,dw7,psel); }

#define MMA_B(b) \
    car##b = __builtin_amdgcn_mfma_f32_16x16x32_f16(aBr, fr##b, z4, 0, 0, 0); \
    cai##b = __builtin_amdgcn_mfma_f32_16x16x32_f16(aBi, fr##b, z4, 0, 0, 0);

// R15: complex 2x2 gate on accumulator pair, explicit f32x2 halves so the
// backend selects v_pk_fma_f32 (gfx90a+ packed FP32): 4 pk insts per output
// half vs 8 scalar FMAs. Same arithmetic, same per-element op order.
#define CGH(o0, o1, o2, o3, ar, ai, br, bi) \
    o0 = g0_*ar - g1_*ai + g2_*br - g3_*bi; \
    o1 = g0_*ai + g1_*ar + g2_*bi + g3_*br; \
    o2 = g4_*ar - g5_*ai + g6_*br - g7_*bi; \
    o3 = g4_*ai + g5_*ar + g6_*bi + g7_*br;

#define CGATE(pa, pb, qp) { \
    const float g0_=(qp)[0], g1_=(qp)[1], g2_=(qp)[2], g3_=(qp)[3]; \
    const float g4_=(qp)[4], g5_=(qp)[5], g6_=(qp)[6], g7_=(qp)[7]; \
    f32x2 arl=lo2(car##pa), ail=lo2(cai##pa), brl=lo2(car##pb), bil=lo2(cai##pb); \
    f32x2 arh=hi2(car##pa), aih=hi2(cai##pa), brh=hi2(car##pb), bih=hi2(cai##pb); \
    f32x2 o0l,o1l,o2l,o3l,o0h,o1h,o2h,o3h; \
    CGH(o0l,o1l,o2l,o3l, arl,ail,brl,bil) \
    CGH(o0h,o1h,o2h,o3h, arh,aih,brh,bih) \
    car##pa = cat4(o0l,o0h); cai##pa = cat4(o1l,o1h); \
    car##pb = cat4(o2l,o2h); cai##pb = cat4(o3l,o3h); }

// layer store to S under φ: k_out = 256b + 64quad + 16r + n
// slot = stb ^ stc_ce(b,r); quad offsets {0,19,24,11} => exact 2-way, free
#define STL(b) { P[stb ^ stc_ce(b,0)] = pkh(car##b.x, cai##b.x); \
                 P[stb ^ stc_ce(b,1)] = pkh(car##b.y, cai##b.y); \
                 P[stb ^ stc_ce(b,2)] = pkh(car##b.z, cai##b.z); \
                 P[stb ^ stc_ce(b,3)] = pkh(car##b.w, cai##b.w); }

// R15: packed readout. Per block: p01/p23 = |amp|^2 pairs (pk mul+fma).
// A01 = Σ_b p01 (r=0,1 components), A23 = Σ_b p23 (r=2,3).
// Then Sx = ΣA, aq4 = (r<2) - (r>=2) = ΣA01 - ΣA23,
// aq5 = (even r) - (odd r) = (A01.x+A23.x) - (A01.y+A23.y).
// aq0/aq1 signs are per-block-uniform => pk accumulate of (p01+p23).
#define ROBPK(b) { \
    f32x2 r01=lo2(car##b), i01=lo2(cai##b), r23=hi2(car##b), i23=hi2(cai##b); \
    f32x2 p01 = r01*r01 + i01*i01; \
    f32x2 p23 = r23*r23 + i23*i23; \
    A01 += p01; A23 += p23; \
    f32x2 ps_ = p01 + p23; \
    if ((b)&2) q0_2 -= ps_; else q0_2 += ps_; \
    if ((b)&1) q1_2 -= ps_; else q1_2 += ps_; }

__global__ __launch_bounds__(TPB)
__attribute__((amdgpu_waves_per_eu(4, 4)))   // R14: (8,8) reverted — forcing a
// 64-VGPR budget caused spills/AGPR copies and a correctness failure.
void vq_main(const float* __restrict__ x, const uint4* __restrict__ frag,
             const float* __restrict__ qcoef, float* __restrict__ out) {
    __shared__ __align__(16) unsigned pl[4][1088];   // wave-private planes
    const int tid = threadIdx.x, wv = tid >> 6, lane = tid & 63;
    unsigned* P = pl[wv];
    const int elem = __builtin_amdgcn_readfirstlane(blockIdx.x * 4 + wv);
    const int n = lane & 15, quad = lane >> 4, q1 = quad & 1;
    const unsigned psel = (lane & 32) ? 0x07060302u : 0x05040100u;

    // perm+swizzle addressing: φ(P(k)) is GF(2)-linear => build φ(PBv) directly
    int PnPhi = 0;
#pragma unroll
    for (int mm = 0; mm < 4; ++mm)
        PnPhi ^= ((n >> mm) & 1) ? phi_ce(cnot_chain_ce(16 << mm)) : 0;
    const int PBvPhi = PnPhi ^ (q1 ? phi_ce(cnot_chain_ce(8)) : 0);
    const int sA  = 272*quad + n;                      // stage-A store base (S')
    const int stb = (quad << 6) ^ g5f_ce(2*quad) ^ n;  // layer store base (S, φ)
    const int ibase = (lane << 4) ^ g5f_ce(lane >> 1); // init store base (S, φ)

    // ---- init: plain product state at slot = φ(k) (perm applied at GATH)
    const float* xr = x + elem * NQ;
    FORALLQ(DECLF)
    FORALLQ(MKF)
    {
        const float pr = (((lane>>5)&1) ? f1_0 : f0_0) * (((lane>>4)&1) ? f1_1 : f0_1)
                       * (((lane>>3)&1) ? f1_2 : f0_2) * (((lane>>2)&1) ? f1_3 : f0_3)
                       * (((lane>>1)&1) ? f1_4 : f0_4) * ((lane&1) ? f1_5 : f0_5);
        // R15: factored 4-bit product table (28 muls vs 64)
        const float cc[4] = { pr * (f0_6*f0_7), pr * (f0_6*f1_7),
                              pr * (f1_6*f0_7), pr * (f1_6*f1_7) };
        const float bb[4] = { f0_8*f0_9, f0_8*f1_9, f1_8*f0_9, f1_8*f1_9 };
        FORALL16(IST)
    }
    LDSFENCE;

    f32x4 car0, car1, car2, car3, cai0, cai1, cai2, cai3;
    const f32x4 z4 = {0.f, 0.f, 0.f, 0.f};

#pragma unroll 1
    for (int l = 0; l < NL; ++l) {
        const uint4* fp = frag + l*4*64;
        const f16x8 aAr = __builtin_bit_cast(f16x8, fp[lane]);
        const f16x8 aAi = __builtin_bit_cast(f16x8, fp[64 + lane]);
        const f16x8 aBr = __builtin_bit_cast(f16x8, fp[128 + lane]);
        const f16x8 aBi = __builtin_bit_cast(f16x8, fp[192 + lane]);
        const float* qc = qcoef + l*16;
        unsigned dw0, dw1, dw2, dw3, dw4, dw5, dw6, dw7;
        f16x8 fr0, fr1, fr2, fr3;

        // stage A: gather (perm+φ fused) ALL blocks, then MFMA+store into S'
        GATH(0) GATH(1) GATH(2) GATH(3)
        LDSFENCE;                          // all S reads done before S' overwrites
        MMA_A(0) MMA_A(1) MMA_A(2) MMA_A(3)
        LDSFENCE;                          // S' stores done before S' reads

        // stage B: adjacent loads from S', MFMA, qubit-0/1 register gates
        GATB(0) GATB(1) GATB(2) GATB(3)
        LDSFENCE;                          // S' reads done before STL overwrites
        MMA_B(0) MMA_B(1) MMA_B(2) MMA_B(3)
        CGATE(0, 1, qc + 8)  CGATE(2, 3, qc + 8)   // qubit 1 (t_hi bit0)
        CGATE(0, 2, qc)      CGATE(1, 3, qc)       // qubit 0 (t_hi bit1)
        if (l < NL - 1) {
            STL(0) STL(1) STL(2) STL(3)            // φ-layout store into S
            LDSFENCE;                      // S stores done before next GATH
        }
    }

    // ---- readout from C regs: k = (16b + 4quad + r)*16 + n
    float Sx, aq0, aq1, aq4, aq5;
    {
        f32x2 A01 = (f32x2){0.f, 0.f}, A23 = (f32x2){0.f, 0.f};
        f32x2 q0_2 = (f32x2){0.f, 0.f}, q1_2 = (f32x2){0.f, 0.f};
        ROBPK(0) ROBPK(1) ROBPK(2) ROBPK(3)
        const float u_ = A01.x + A01.y, v_ = A23.x + A23.y;
        Sx  = u_ + v_;
        aq4 = u_ - v_;
        aq5 = (A01.x + A23.x) - (A01.y + A23.y);
        aq0 = q0_2.x + q0_2.y;
        aq1 = q1_2.x + q1_2.y;
    }

    // R15: shared butterfly — sum-channel `cur` spawns signed outputs per level
    // (level masks 1..32 <-> lane bits 0..5 <-> w9,w8,w7,w6,w3,w2)
    float d9, d8, d7, d6, d3, d2;
    float cur = Sx;
    SPAWN(1, d9) SPAWN(2, d8) SPAWN(4, d7) SPAWN(8, d6) SPAWN(16, d3) SPAWN(32, d2)
    WR1(d9,2) WR1(d9,4) WR1(d9,8) WR1(d9,16) WR1(d9,32)
    WR1(d8,4) WR1(d8,8) WR1(d8,16) WR1(d8,32)
    WR1(d7,8) WR1(d7,16) WR1(d7,32)
    WR1(d6,16) WR1(d6,32)
    WR1(d3,32)
    WRED(aq0) WRED(aq1) WRED(aq4) WRED(aq5)
    if (lane == 0) {
        float* op = out + elem * NQ;
        op[0] = aq0; op[1] = aq1; op[2] = d2; op[3] = d3; op[4] = aq4;
        op[5] = aq5; op[6] = d6; op[7] = d7; op[8] = d8; op[9] = d9;
    }
}

extern "C" void kernel_launch(void* const* d_in, const int* in_sizes, int n_in,
                              void* d_out, int out_size, void* d_ws, size_t ws_size,
                              hipStream_t stream) {
    const float* x = (const float*)d_in[0];   // (16384, 10) fp32
    const float* w = (const float*)d_in[1];   // (3, 10, 3) fp32
    float* out = (float*)d_out;               // (16384, 10) fp32
    uint4* frag = (uint4*)d_ws;               // 768 uint4 = 12 KB A-fragments
    float* qcoef = (float*)((char*)d_ws + 768 * sizeof(uint4));   // 48 floats
    const int B = in_sizes[0] / NQ;           // 16384
    vq_prep<<<dim3(1), dim3(TPB), 0, stream>>>(w, frag, qcoef);
    vq_main<<<dim3(B / 4), dim3(TPB), 0, stream>>>(x, frag, qcoef, out);
}

// Round 4
// 94.739 us; speedup vs baseline: 1.0557x; 1.0125x over previous
//
#include <hip/hip_runtime.h>
#include <math.h>

#define NQ 10
#define NL 3
#define PI_F 3.14159265358979f
#define TPB 256   // 4 waves/block; ONE batch element per wave

typedef _Float16 f16x8 __attribute__((ext_vector_type(8)));
typedef _Float16 h2t  __attribute__((ext_vector_type(2)));
typedef float    f32x4 __attribute__((ext_vector_type(4)));
typedef float    f32x2 __attribute__((ext_vector_type(2)));

// Compiler memory barrier + LDS drain: optimizer cannot move LDS ops across,
// hardware guarantees all prior DS ops complete. (wave_barrier is NOT a memory
// fence — R11/R12 failed because typed loads were hoisted across stores.)
#define LDSFENCE asm volatile("s_waitcnt lgkmcnt(0)" ::: "memory")

// Composed CNOT-ring permutation (GF(2)-linear), compile-time only.
__host__ __device__ constexpr int cnot_chain_ce(int j) {
    for (int i = NQ - 1; i >= 0; --i) {
        int tq = (i + 1) % NQ;
        j ^= ((j >> (NQ - 1 - i)) & 1) << (NQ - 1 - tq);
    }
    return j;
}

// ---- S-layout bank swizzle (R13/R14-verified) ----------------------------
// slot(k) = φ(k) = k ^ g5(k>>5), GF(2)-linear, bijective on [0,1024).
// GATH bank generators {12,24,17,18,11}: rank 5 => conflict-free gathers.
// IST exact 2-way (free); STL exact 2-way. Measured: conflicts 1.21e7->1.57e6.
__host__ __device__ constexpr int g5f_ce(int h) {
    return ((h & 1) ? 1 : 0) ^ ((h & 2) ? 19 : 0) ^ ((h & 4) ? 24 : 0)
         ^ ((h & 8) ? 4 : 0) ^ ((h & 16) ? 2 : 0);
}
__host__ __device__ constexpr int phi_ce(int k) { return k ^ g5f_ce(k >> 5); }
// STL store offset: φ(256b) ^ φ(16r) (disjoint bit-fields => XOR-separable)
__host__ __device__ constexpr int stc_ce(int b, int r) {
    return phi_ce(256 * (b)) ^ phi_ce(16 * (r));
}

__device__ __forceinline__ unsigned pkh(float r, float i) {
    return __builtin_bit_cast(unsigned, __builtin_amdgcn_cvt_pkrtz(r, i));
}

// f32x4 <-> f32x2 half helpers (register-aliasing; no data movement expected)
__device__ __forceinline__ f32x2 lo2(f32x4 v) { f32x2 r; r.x = v.x; r.y = v.y; return r; }
__device__ __forceinline__ f32x2 hi2(f32x4 v) { f32x2 r; r.x = v.z; r.y = v.w; return r; }
__device__ __forceinline__ f32x4 cat4(f32x2 a, f32x2 b) {
    f32x4 r; r.x = a.x; r.y = a.y; r.z = b.x; r.w = b.y; return r;
}

// Build a B-fragment (f16x8): element e = selected f16 half of dw[e].
// psel picks lo halves (re-plane lanes) or hi halves (im-plane lanes).
__device__ __forceinline__ f16x8 mkfrag(unsigned d0, unsigned d1, unsigned d2,
                                        unsigned d3, unsigned d4, unsigned d5,
                                        unsigned d6, unsigned d7, unsigned sel) {
    uint4 u;
    u.x = __builtin_amdgcn_perm(d1, d0, sel);
    u.y = __builtin_amdgcn_perm(d3, d2, sel);
    u.z = __builtin_amdgcn_perm(d5, d4, sel);
    u.w = __builtin_amdgcn_perm(d7, d6, sel);
    return __builtin_bit_cast(f16x8, u);
}

// lane-xor exchange for the final reduction: 1,2,4,8 DPP; 16 swizzle; 32 shfl
template<int MASK>
__device__ __forceinline__ unsigned lxu(unsigned v) {
    if constexpr (MASK == 1)
        return (unsigned)__builtin_amdgcn_update_dpp(0, (int)v, 0xB1, 0xF, 0xF, true);
    else if constexpr (MASK == 2)
        return (unsigned)__builtin_amdgcn_update_dpp(0, (int)v, 0x4E, 0xF, 0xF, true);
    else if constexpr (MASK == 4) {
        int a = __builtin_amdgcn_update_dpp(0, (int)v, 0x1B, 0xF, 0xF, true);
        return (unsigned)__builtin_amdgcn_update_dpp(0, a, 0x141, 0xF, 0xF, true);
    } else if constexpr (MASK == 8) {
        int a = __builtin_amdgcn_update_dpp(0, (int)v, 0x141, 0xF, 0xF, true);
        return (unsigned)__builtin_amdgcn_update_dpp(0, a, 0x140, 0xF, 0xF, true);
    } else if constexpr (MASK == 16)
        return (unsigned)__builtin_amdgcn_ds_swizzle((int)v, 0x401F);
    else
        return (unsigned)__shfl_xor((int)v, 32, 64);
}
#define WR1(v, M) v += __builtin_bit_cast(float, lxu<M>(__builtin_bit_cast(unsigned, v)));
#define WRED(v) { WR1(v,1) WR1(v,2) WR1(v,4) WR1(v,8) WR1(v,16) WR1(v,32) }
// R15: shared butterfly with difference-spawn. At each level, the sum-channel
// and the signed output share the same shuffle; lane 0 (all bits 0) always
// carries the + convention, so per-lane sign skew in D cancels at readout.
#define SPAWN(M, D) { float t_ = __builtin_bit_cast(float, lxu<M>(__builtin_bit_cast(unsigned, cur))); \
    D = cur - t_; cur += t_; }

#define FORALL16(F) F(0) F(1) F(2) F(3) F(4) F(5) F(6) F(7) \
                    F(8) F(9) F(10) F(11) F(12) F(13) F(14) F(15)
#define FORALLQ(F) F(0) F(1) F(2) F(3) F(4) F(5) F(6) F(7) F(8) F(9)

// ============ prep: fused gate matrices -> MFMA A-fragments (R10-verified) ============
__global__ void vq_prep(const float* __restrict__ w, uint4* __restrict__ frag,
                        float* __restrict__ qcoef) {
    __shared__ float msh[NL * NQ][8];
    const int tid = threadIdx.x;
    if (tid < NL * NQ) {
        const float* wp = w + tid * 3;
        float sa = __sinf(wp[0]*0.5f), ca = __cosf(wp[0]*0.5f);
        float sb = __sinf(wp[1]*0.5f), cb = __cosf(wp[1]*0.5f);
        float sc = __sinf(wp[2]*0.5f), cc = __cosf(wp[2]*0.5f);
        float c00r = cb*ca,  c00i =  sa*sb;
        float c01r = -sb*ca, c01i = -cb*sa;
        float c10r =  sb*ca, c10i = -cb*sa;
        float c11r =  cb*ca, c11i = -sb*sa;
        float m[8];
        m[0] = cc*c00r + sc*c00i;  m[1] = cc*c00i - sc*c00r;
        m[2] = cc*c01r + sc*c01i;  m[3] = cc*c01i - sc*c01r;
        m[4] = cc*c10r - sc*c10i;  m[5] = cc*c10i + sc*c10r;
        m[6] = cc*c11r - sc*c11i;  m[7] = cc*c11i + sc*c11r;
#pragma unroll
        for (int j = 0; j < 8; ++j) msh[tid][j] = m[j];
        const int l = tid / NQ, q = tid % NQ;
        if (q < 2)
#pragma unroll
            for (int j = 0; j < 8; ++j) qcoef[(l*2 + q)*8 + j] = m[j];
    }
    __syncthreads();
    const int lane = tid & 63, wg = tid >> 6;
    const int mrow = lane & 15, quad = lane >> 4;
#pragma unroll 1
    for (int c = 0; c < 3; ++c) {
        const int id = c*4 + wg;            // id = l*4 + s*2 + v
        const int l = id >> 2, s = (id >> 1) & 1, v = id & 1;
        const int qb = s ? 2 : 6;
        unsigned pd[4];
#pragma unroll
        for (int d = 0; d < 4; ++d) {
            float hv[2];
#pragma unroll
            for (int h = 0; h < 2; ++h) {
                const int k = quad*8 + 2*d + h;
                const int col = k & 15;
                float er = 1.f, ei = 0.f;
#pragma unroll
                for (int p = 0; p < 4; ++p) {
                    const float* mm = msh[l*NQ + qb + p];
                    const int rb = (mrow >> (3-p)) & 1, cb2 = (col >> (3-p)) & 1;
                    const float gr = mm[(rb*2 + cb2)*2], gi = mm[(rb*2 + cb2)*2 + 1];
                    const float nr = er*gr - ei*gi, ni = er*gi + ei*gr;
                    er = nr; ei = ni;
                }
                hv[h] = (k < 16) ? (v ? ei : er) : (v ? er : -ei);
            }
            h2t hh; hh.x = (_Float16)hv[0]; hh.y = (_Float16)hv[1];
            pd[d] = __builtin_bit_cast(unsigned, hh);
        }
        frag[id*64 + lane] = make_uint4(pd[0], pd[1], pd[2], pd[3]);
    }
}

// ============ main kernel ============
// R16: DISJOINT S / S' planes. S = P[0,1024) holds the inter-layer state at
// slot φ(k); S' = Q[0,1084) (P+1024) holds the intra-layer j'-major tile.
// With no aliasing, the WAR fences (GATH->MMA_A stores, GATB->STL stores)
// are deleted: 12 lgkmcnt(0) drains/wave -> 6. Remaining fences are true RAW:
//   init IST -> first GATH (S), MMA_A -> GATB (S'), STL -> next GATH (S).
// GATB upgraded to 2x ds_read_b128 (16B-aligned; span = n+2q1+4b mod 8 is
// uniform => conflict-free). uint4/unsigned TBAA mix is safe: the RAW
// LDSFENCE (full "memory" clobber) sits between the stores and these loads.
// Cost: LDS 17408 -> 33792 B/block => residency cap 4 blocks/CU = 16 waves/CU,
// above the measured ~10.4/CU average.

#define DECLF(q) float f0_##q, f1_##q;
#define MKF(q) { float e_ = __expf(2.0f * xr[q]); \
    float h_ = (1.0f - 2.0f / (e_ + 1.0f)) * (PI_F * 0.5f); \
    f1_##q = __sinf(h_); f0_##q = __cosf(h_); }

// R15: factored init products — cc[J>>2] * bb[J&3] (literal J => static index)
#define IST(J) { float a_ = cc[(J) >> 2] * bb[(J) & 3]; \
    P[ibase ^ (J)] = pkh(a_, 0.0f); }

// stage-A gather with perm + φ fused: slot = φ(PBv) ^ φ(P(256b) ^ P(i))
// bank generators {24,17,18,11,12} rank-5 => conflict-free (enumeration)
#define LDA1(b,i) { constexpr int sc_ = phi_ce(cnot_chain_ce((b)*256) ^ cnot_chain_ce(i)); \
    dw##i = P[PBvPhi ^ sc_]; }
#define GATH(b) LDA1(b,0) LDA1(b,1) LDA1(b,2) LDA1(b,3) LDA1(b,4) LDA1(b,5) LDA1(b,6) LDA1(b,7) \
    fr##b = mkfrag(dw0,dw1,dw2,dw3,dw4,dw5,dw6,dw7,psel);

// stage-A MFMA + store to S' (j'-major): slot = 68*(4quad+r) + 16b + n
// per-instruction bank = (16*quad + n) mod 32 -> exact 2-way, free
#define MMA_A(b) { \
    f32x4 cr_ = __builtin_amdgcn_mfma_f32_16x16x32_f16(aAr, fr##b, z4, 0, 0, 0); \
    f32x4 ci_ = __builtin_amdgcn_mfma_f32_16x16x32_f16(aAi, fr##b, z4, 0, 0, 0); \
    Q[sA + 16*(b)      ] = pkh(cr_.x, ci_.x); \
    Q[sA + 16*(b) +  68] = pkh(cr_.y, ci_.y); \
    Q[sA + 16*(b) + 136] = pkh(cr_.z, ci_.z); \
    Q[sA + 16*(b) + 204] = pkh(cr_.w, ci_.w); }

// stage-B gather: 8 adjacent dwords as 2x ds_read_b128 (R16).
// slot = 68n + 8q1 + 16b + i; 16B-aligned; spans uniform mod 8 => conflict-free.
#define GATB(b) { const uint4* q4_ = (const uint4*)(Q + 68*n + 8*q1 + 16*(b)); \
    const uint4 ua_ = q4_[0], ub_ = q4_[1]; \
    fr##b = mkfrag(ua_.x, ua_.y, ua_.z, ua_.w, ub_.x, ub_.y, ub_.z, ub_.w, psel); }

#define MMA_B(b) \
    car##b = __builtin_amdgcn_mfma_f32_16x16x32_f16(aBr, fr##b, z4, 0, 0, 0); \
    cai##b = __builtin_amdgcn_mfma_f32_16x16x32_f16(aBi, fr##b, z4, 0, 0, 0);

// R15: complex 2x2 gate on accumulator pair, explicit f32x2 halves so the
// backend selects v_pk_fma_f32 (gfx90a+ packed FP32): 4 pk insts per output
// half vs 8 scalar FMAs. Same arithmetic, same per-element op order.
#define CGH(o0, o1, o2, o3, ar, ai, br, bi) \
    o0 = g0_*ar - g1_*ai + g2_*br - g3_*bi; \
    o1 = g0_*ai + g1_*ar + g2_*bi + g3_*br; \
    o2 = g4_*ar - g5_*ai + g6_*br - g7_*bi; \
    o3 = g4_*ai + g5_*ar + g6_*bi + g7_*br;

#define CGATE(pa, pb, qp) { \
    const float g0_=(qp)[0], g1_=(qp)[1], g2_=(qp)[2], g3_=(qp)[3]; \
    const float g4_=(qp)[4], g5_=(qp)[5], g6_=(qp)[6], g7_=(qp)[7]; \
    f32x2 arl=lo2(car##pa), ail=lo2(cai##pa), brl=lo2(car##pb), bil=lo2(cai##pb); \
    f32x2 arh=hi2(car##pa), aih=hi2(cai##pa), brh=hi2(car##pb), bih=hi2(cai##pb); \
    f32x2 o0l,o1l,o2l,o3l,o0h,o1h,o2h,o3h; \
    CGH(o0l,o1l,o2l,o3l, arl,ail,brl,bil) \
    CGH(o0h,o1h,o2h,o3h, arh,aih,brh,bih) \
    car##pa = cat4(o0l,o0h); cai##pa = cat4(o1l,o1h); \
    car##pb = cat4(o2l,o2h); cai##pb = cat4(o3l,o3h); }

// layer store to S under φ: k_out = 256b + 64quad + 16r + n
// slot = stb ^ stc_ce(b,r); quad offsets {0,19,24,11} => exact 2-way, free
#define STL(b) { P[stb ^ stc_ce(b,0)] = pkh(car##b.x, cai##b.x); \
                 P[stb ^ stc_ce(b,1)] = pkh(car##b.y, cai##b.y); \
                 P[stb ^ stc_ce(b,2)] = pkh(car##b.z, cai##b.z); \
                 P[stb ^ stc_ce(b,3)] = pkh(car##b.w, cai##b.w); }

// R15: packed readout. Per block: p01/p23 = |amp|^2 pairs (pk mul+fma).
// A01 = Σ_b p01 (r=0,1 components), A23 = Σ_b p23 (r=2,3).
// Then Sx = ΣA, aq4 = (r<2) - (r>=2) = ΣA01 - ΣA23,
// aq5 = (even r) - (odd r) = (A01.x+A23.x) - (A01.y+A23.y).
// aq0/aq1 signs are per-block-uniform => pk accumulate of (p01+p23).
#define ROBPK(b) { \
    f32x2 r01=lo2(car##b), i01=lo2(cai##b), r23=hi2(car##b), i23=hi2(cai##b); \
    f32x2 p01 = r01*r01 + i01*i01; \
    f32x2 p23 = r23*r23 + i23*i23; \
    A01 += p01; A23 += p23; \
    f32x2 ps_ = p01 + p23; \
    if ((b)&2) q0_2 -= ps_; else q0_2 += ps_; \
    if ((b)&1) q1_2 -= ps_; else q1_2 += ps_; }

__global__ __launch_bounds__(TPB)
__attribute__((amdgpu_waves_per_eu(4, 4)))   // R14: (8,8) reverted — forcing a
// 64-VGPR budget caused spills/AGPR copies and a correctness failure.
void vq_main(const float* __restrict__ x, const uint4* __restrict__ frag,
             const float* __restrict__ qcoef, float* __restrict__ out) {
    // R16: 2112 dwords/wave = S[1024] + S'[1088] (disjoint; S' base ≡ 0 mod 32
    // banks so all prior bank derivations hold unchanged)
    __shared__ __align__(16) unsigned pl[4][2112];
    const int tid = threadIdx.x, wv = tid >> 6, lane = tid & 63;
    unsigned* P = pl[wv];
    unsigned* Q = P + 1024;
    const int elem = __builtin_amdgcn_readfirstlane(blockIdx.x * 4 + wv);
    const int n = lane & 15, quad = lane >> 4, q1 = quad & 1;
    const unsigned psel = (lane & 32) ? 0x07060302u : 0x05040100u;

    // perm+swizzle addressing: φ(P(k)) is GF(2)-linear => build φ(PBv) directly
    int PnPhi = 0;
#pragma unroll
    for (int mm = 0; mm < 4; ++mm)
        PnPhi ^= ((n >> mm) & 1) ? phi_ce(cnot_chain_ce(16 << mm)) : 0;
    const int PBvPhi = PnPhi ^ (q1 ? phi_ce(cnot_chain_ce(8)) : 0);
    const int sA  = 272*quad + n;                      // stage-A store base (S')
    const int stb = (quad << 6) ^ g5f_ce(2*quad) ^ n;  // layer store base (S, φ)
    const int ibase = (lane << 4) ^ g5f_ce(lane >> 1); // init store base (S, φ)

    // ---- init: plain product state at slot = φ(k) (perm applied at GATH)
    const float* xr = x + elem * NQ;
    FORALLQ(DECLF)
    FORALLQ(MKF)
    {
        const float pr = (((lane>>5)&1) ? f1_0 : f0_0) * (((lane>>4)&1) ? f1_1 : f0_1)
                       * (((lane>>3)&1) ? f1_2 : f0_2) * (((lane>>2)&1) ? f1_3 : f0_3)
                       * (((lane>>1)&1) ? f1_4 : f0_4) * ((lane&1) ? f1_5 : f0_5);
        // R15: factored 4-bit product table (28 muls vs 64)
        const float cc[4] = { pr * (f0_6*f0_7), pr * (f0_6*f1_7),
                              pr * (f1_6*f0_7), pr * (f1_6*f1_7) };
        const float bb[4] = { f0_8*f0_9, f0_8*f1_9, f1_8*f0_9, f1_8*f1_9 };
        FORALL16(IST)
    }
    LDSFENCE;                              // RAW: IST(S) -> first GATH(S)

    f32x4 car0, car1, car2, car3, cai0, cai1, cai2, cai3;
    const f32x4 z4 = {0.f, 0.f, 0.f, 0.f};

#pragma unroll 1
    for (int l = 0; l < NL; ++l) {
        const uint4* fp = frag + l*4*64;
        const f16x8 aAr = __builtin_bit_cast(f16x8, fp[lane]);
        const f16x8 aAi = __builtin_bit_cast(f16x8, fp[64 + lane]);
        const f16x8 aBr = __builtin_bit_cast(f16x8, fp[128 + lane]);
        const f16x8 aBi = __builtin_bit_cast(f16x8, fp[192 + lane]);
        const float* qc = qcoef + l*16;
        unsigned dw0, dw1, dw2, dw3, dw4, dw5, dw6, dw7;
        f16x8 fr0, fr1, fr2, fr3;

        // stage A: gather from S (perm+φ fused), MFMA, store into DISJOINT S'.
        // R16: no fence between GATH reads and MMA_A stores (no aliasing).
        GATH(0) GATH(1) GATH(2) GATH(3)
        MMA_A(0) MMA_A(1) MMA_A(2) MMA_A(3)
        LDSFENCE;                          // RAW: S' stores -> S' reads

        // stage B: b128 loads from S', MFMA, qubit-0/1 register gates.
        // R16: no fence after GATB (STL writes S, disjoint from S').
        GATB(0) GATB(1) GATB(2) GATB(3)
        MMA_B(0) MMA_B(1) MMA_B(2) MMA_B(3)
        CGATE(0, 1, qc + 8)  CGATE(2, 3, qc + 8)   // qubit 1 (t_hi bit0)
        CGATE(0, 2, qc)      CGATE(1, 3, qc)       // qubit 0 (t_hi bit1)
        if (l < NL - 1) {
            STL(0) STL(1) STL(2) STL(3)            // φ-layout store into S
            LDSFENCE;                      // RAW: S stores -> next GATH
        }
    }

    // ---- readout from C regs: k = (16b + 4quad + r)*16 + n
    float Sx, aq0, aq1, aq4, aq5;
    {
        f32x2 A01 = (f32x2){0.f, 0.f}, A23 = (f32x2){0.f, 0.f};
        f32x2 q0_2 = (f32x2){0.f, 0.f}, q1_2 = (f32x2){0.f, 0.f};
        ROBPK(0) ROBPK(1) ROBPK(2) ROBPK(3)
        const float u_ = A01.x + A01.y, v_ = A23.x + A23.y;
        Sx  = u_ + v_;
        aq4 = u_ - v_;
        aq5 = (A01.x + A23.x) - (A01.y + A23.y);
        aq0 = q0_2.x + q0_2.y;
        aq1 = q1_2.x + q1_2.y;
    }

    // R15: shared butterfly — sum-channel `cur` spawns signed outputs per level
    // (level masks 1..32 <-> lane bits 0..5 <-> w9,w8,w7,w6,w3,w2)
    float d9, d8, d7, d6, d3, d2;
    float cur = Sx;
    SPAWN(1, d9) SPAWN(2, d8) SPAWN(4, d7) SPAWN(8, d6) SPAWN(16, d3) SPAWN(32, d2)
    WR1(d9,2) WR1(d9,4) WR1(d9,8) WR1(d9,16) WR1(d9,32)
    WR1(d8,4) WR1(d8,8) WR1(d8,16) WR1(d8,32)
    WR1(d7,8) WR1(d7,16) WR1(d7,32)
    WR1(d6,16) WR1(d6,32)
    WR1(d3,32)
    WRED(aq0) WRED(aq1) WRED(aq4) WRED(aq5)
    if (lane == 0) {
        float* op = out + elem * NQ;
        op[0] = aq0; op[1] = aq1; op[2] = d2; op[3] = d3; op[4] = aq4;
        op[5] = aq5; op[6] = d6; op[7] = d7; op[8] = d8; op[9] = d9;
    }
}

extern "C" void kernel_launch(void* const* d_in, const int* in_sizes, int n_in,
                              void* d_out, int out_size, void* d_ws, size_t ws_size,
                              hipStream_t stream) {
    const float* x = (const float*)d_in[0];   // (16384, 10) fp32
    const float* w = (const float*)d_in[1];   // (3, 10, 3) fp32
    float* out = (float*)d_out;               // (16384, 10) fp32
    uint4* frag = (uint4*)d_ws;               // 768 uint4 = 12 KB A-fragments
    float* qcoef = (float*)((char*)d_ws + 768 * sizeof(uint4));   // 48 floats
    const int B = in_sizes[0] / NQ;           // 16384
    vq_prep<<<dim3(1), dim3(TPB), 0, stream>>>(w, frag, qcoef);
    vq_main<<<dim3(B / 4), dim3(TPB), 0, stream>>>(x, frag, qcoef, out);
}